// Round 4
// baseline (37.639 us; speedup 1.0000x reference)
//
#include <hip/hip_runtime.h>

// RandomCrop (integer shift with zero padding):
//   out[n,c,i,j] = in[n,c, i+sy, j+sx] if in-range else 0
//   sx = shifts[n,0]-8, sy = shifts[n,1]-8. N=128,C=3,H=256,W=256 fp32.
// One wave handles 8 consecutive rows of ONE plane (8 divides 256, so a
// chunk never crosses a plane boundary -> n, sx, sy are wave-uniform and
// computed once). 32 independent dword loads in flight per wave,
// branchless clamped addresses + cndmask zeroing, nontemporal dwordx4
// stores. Exact-cover grid, no tail handling.

#define MAXPIX 8
#define W 256
#define H 256
#define CCH 3

typedef float f32x4 __attribute__((ext_vector_type(4)));

__global__ __launch_bounds__(256) void shift_kernel(
    const float* __restrict__ in,
    const int* __restrict__ shifts,
    float* __restrict__ out)
{
    const int lane = threadIdx.x & 63;
    const int wid  = threadIdx.x >> 6;              // wave in block, 0..3
    constexpr int R = 8;                            // rows per wave
    const int row0 = (blockIdx.x * 4 + wid) * R;    // multiple of 8, exact cover

    // Whole 8-row chunk lives in one plane: uniform scalars, computed once.
    const int nc = row0 >> 8;                       // n*C + c
    const int n  = __builtin_amdgcn_readfirstlane(nc / CCH);
    const int sx = shifts[2 * n]     - MAXPIX;      // s_load path
    const int sy = shifts[2 * n + 1] - MAXPIX;
    const int i0 = row0 & (H - 1);

    const float* __restrict__ srcplane = in + (long)nc * (H * W);

    // Column addresses/validity: identical for all 8 rows.
    const int  j0  = (lane << 2) + sx;
    const int  jc0 = min(max(j0 + 0, 0), W - 1);
    const int  jc1 = min(max(j0 + 1, 0), W - 1);
    const int  jc2 = min(max(j0 + 2, 0), W - 1);
    const int  jc3 = min(max(j0 + 3, 0), W - 1);
    const bool vx0 = (unsigned)(j0 + 0) < (unsigned)W;
    const bool vx1 = (unsigned)(j0 + 1) < (unsigned)W;
    const bool vx2 = (unsigned)(j0 + 2) < (unsigned)W;
    const bool vx3 = (unsigned)(j0 + 3) < (unsigned)W;

    f32x4 v[R];

    #pragma unroll
    for (int r = 0; r < R; ++r) {
        const int  syr = i0 + r + sy;
        const int  syc = min(max(syr, 0), H - 1);   // clamped: always in-bounds
        const bool vy  = (unsigned)syr < (unsigned)H;

        const float* __restrict__ src = srcplane + syc * W;
        // 4 unconditional dword loads, zeroed by cndmask afterwards.
        const float x0 = src[jc0], x1 = src[jc1], x2 = src[jc2], x3 = src[jc3];
        v[r].x = (vy && vx0) ? x0 : 0.f;
        v[r].y = (vy && vx1) ? x1 : 0.f;
        v[r].z = (vy && vx2) ? x2 : 0.f;
        v[r].w = (vy && vx3) ? x3 : 0.f;
    }

    float* dst = out + (long)row0 * W + (lane << 2);
    #pragma unroll
    for (int r = 0; r < R; ++r) {
        // Write-once streaming output: nontemporal dwordx4, keep input in cache.
        __builtin_nontemporal_store(v[r], reinterpret_cast<f32x4*>(dst + r * W));
    }
}

extern "C" void kernel_launch(void* const* d_in, const int* in_sizes, int n_in,
                              void* d_out, int out_size, void* d_ws, size_t ws_size,
                              hipStream_t stream) {
    const float* in     = (const float*)d_in[0];
    const int*   shifts = (const int*)d_in[1];
    float*       out    = (float*)d_out;

    const int total_rows = out_size / W;            // N*C*H = 98304
    // Exact cover: block = 4 waves x 8 rows = 32 rows. 98304/32 = 3072 blocks.
    const int blocks = total_rows / 32;

    shift_kernel<<<dim3(blocks), dim3(256), 0, stream>>>(in, shifts, out);
}

// Round 5
// 34.579 us; speedup vs baseline: 1.0885x; 1.0885x over previous
//
#include <hip/hip_runtime.h>

// RandomCrop (integer shift with zero padding):
//   out[n,c,i,j] = in[n,c, i+sy, j+sx] if in-range else 0
//   sx = shifts[n,0]-8, sy = shifts[n,1]-8. N=128,C=3,H=256,W=256 fp32.
// One wave = 8 consecutive rows of one plane (8 | 256 -> never crosses a
// plane boundary; n, sx, sy wave-uniform). Per row: ONE unaligned
// global_load_dwordx4 (gfx950 allows 4B-aligned dwordx4) instead of 4
// scalar dwords; <=2 fringe lanes per wave take a rare exec-masked scalar
// fixup. Nontemporal dwordx4 stores. Exact-cover grid.

#define MAXPIX 8
#define W 256
#define H 256
#define CCH 3

typedef float f32x4 __attribute__((ext_vector_type(4)));

__global__ __launch_bounds__(256) void shift_kernel(
    const float* __restrict__ in,
    const int* __restrict__ shifts,
    float* __restrict__ out)
{
    const int lane = threadIdx.x & 63;
    const int wid  = threadIdx.x >> 6;              // wave in block, 0..3
    constexpr int R = 8;                            // rows per wave
    const int row0 = (blockIdx.x * 4 + wid) * R;    // multiple of 8, exact cover

    // Whole 8-row chunk lives in one plane: uniform scalars, computed once.
    const int nc = row0 >> 8;                       // n*C + c
    const int n  = __builtin_amdgcn_readfirstlane(nc / CCH);
    const int sx = shifts[2 * n]     - MAXPIX;      // s_load path
    const int sy = shifts[2 * n + 1] - MAXPIX;
    const int i0 = row0 & (H - 1);

    const float* __restrict__ srcplane = in + (long)nc * (H * W);

    // Column geometry: identical for all 8 rows.
    const int  j0  = (lane << 2) + sx;              // wanted start col of 4-elem chunk
    const int  jb  = min(max(j0, 0), W - 4);        // clamped, always-safe vector base
    const bool fix = (j0 != jb);                    // true on <=2 lanes per wave
    const int  jc0 = min(max(j0 + 0, 0), W - 1);    // scalar-clamped (fixup path)
    const int  jc1 = min(max(j0 + 1, 0), W - 1);
    const int  jc2 = min(max(j0 + 2, 0), W - 1);
    const int  jc3 = min(max(j0 + 3, 0), W - 1);
    const bool vx0 = (unsigned)(j0 + 0) < (unsigned)W;
    const bool vx1 = (unsigned)(j0 + 1) < (unsigned)W;
    const bool vx2 = (unsigned)(j0 + 2) < (unsigned)W;
    const bool vx3 = (unsigned)(j0 + 3) < (unsigned)W;

    f32x4 v[R];

    #pragma unroll
    for (int r = 0; r < R; ++r) {
        const int  syr = i0 + r + sy;
        const int  syc = min(max(syr, 0), H - 1);   // clamped: always in-bounds
        const bool vy  = (unsigned)syr < (unsigned)H;

        const float* __restrict__ src = srcplane + syc * W;

        // One unaligned (4B-aligned) dwordx4 load covers the interior case.
        f32x4 t;
        __builtin_memcpy(&t, src + jb, sizeof(f32x4));
        if (fix) {                                  // <=2 lanes: exec-masked scalars
            t.x = src[jc0];
            t.y = src[jc1];
            t.z = src[jc2];
            t.w = src[jc3];
        }

        v[r].x = (vy && vx0) ? t.x : 0.f;
        v[r].y = (vy && vx1) ? t.y : 0.f;
        v[r].z = (vy && vx2) ? t.z : 0.f;
        v[r].w = (vy && vx3) ? t.w : 0.f;
    }

    float* dst = out + (long)row0 * W + (lane << 2);
    #pragma unroll
    for (int r = 0; r < R; ++r) {
        // Write-once streaming output: nontemporal dwordx4.
        __builtin_nontemporal_store(v[r], reinterpret_cast<f32x4*>(dst + r * W));
    }
}

extern "C" void kernel_launch(void* const* d_in, const int* in_sizes, int n_in,
                              void* d_out, int out_size, void* d_ws, size_t ws_size,
                              hipStream_t stream) {
    const float* in     = (const float*)d_in[0];
    const int*   shifts = (const int*)d_in[1];
    float*       out    = (float*)d_out;

    const int total_rows = out_size / W;            // N*C*H = 98304
    // Exact cover: block = 4 waves x 8 rows = 32 rows. 98304/32 = 3072 blocks.
    const int blocks = total_rows / 32;

    shift_kernel<<<dim3(blocks), dim3(256), 0, stream>>>(in, shifts, out);
}